// Round 6
// baseline (3011.227 us; speedup 1.0000x reference)
//
#include <hip/hip_runtime.h>

#define BN 8
#define NN 4096
#define CC 64
#define MM 1024
#define KK 64
#define HH 128

typedef __attribute__((ext_vector_type(8))) short short8;
typedef __attribute__((ext_vector_type(4))) float f32x4;
typedef __attribute__((ext_vector_type(2))) float f32x2;
typedef unsigned long long u64;
typedef unsigned int u32;

__device__ inline unsigned short f2bf(float f) {
  union { float f; unsigned u; } v; v.f = f;
  unsigned r = v.u + 0x7FFFu + ((v.u >> 16) & 1u);
  return (unsigned short)(r >> 16);
}

// squared distance with NO fma contraction, numpy op order: (dx*dx + dy*dy) + dz*dz
__device__ inline float sqd(float ax, float ay, float az, float bx, float by, float bz) {
  float dx = __fsub_rn(ax, bx), dy = __fsub_rn(ay, by), dz = __fsub_rn(az, bz);
  return __fadd_rn(__fadd_rn(__fmul_rn(dx, dx), __fmul_rn(dy, dy)), __fmul_rn(dz, dz));
}

// ---------------- weight prep: transpose + pad + bf16 ----------------
__global__ void prep_w(const float* __restrict__ W1, const float* __restrict__ W2,
                       short* __restrict__ W1T, short* __restrict__ W2T) {
  int t = blockIdx.x * 256 + threadIdx.x;
  if (t < 128 * 104) {
    int n = t / 104, k = t % 104;
    float v = (k < 67) ? W1[k * 128 + n] : 0.f;
    W1T[t] = (short)f2bf(v);
  }
  if (t < 128 * 136) {
    int n = t / 136, k = t % 136;
    float v = (k < 128) ? W2[k * 128 + n] : 0.f;
    W2T[t] = (short)f2bf(v);
  }
}

// ---- DPP-based wave max of f32 (result broadcast via readlane 63) ----
template <int CTRL, int RM>
__device__ __forceinline__ float dppf(float x) {
  int v = __builtin_amdgcn_update_dpp(0, __float_as_int(x), CTRL, RM, 0xF, false);
  return __int_as_float(v);
}

__device__ __forceinline__ float wave_fmax(float x) {
  x = fmaxf(x, dppf<0xB1, 0xF>(x));    // quad_perm xor1
  x = fmaxf(x, dppf<0x4E, 0xF>(x));    // quad_perm xor2
  x = fmaxf(x, dppf<0x141, 0xF>(x));   // row_half_mirror
  x = fmaxf(x, dppf<0x140, 0xF>(x));   // row_mirror
  x = fmaxf(x, dppf<0x142, 0xA>(x));   // row_bcast15 -> rows 1,3
  x = fmaxf(x, dppf<0x143, 0xC>(x));   // row_bcast31 -> rows 2,3
  return __int_as_float(__builtin_amdgcn_readlane(__float_as_int(x), 63));
}

// key: low word = ~idx, high word = dist bits; both dist>=0 -> u64 order == f64 order
__device__ __forceinline__ double keyd(f32x4 e) {
  f32x2 p; p.x = e[0]; p.y = e[1];
  return __builtin_bit_cast(double, p);
}

// per-wave reduce: find wave winner (max dist, lowest idx), winner lane writes
// {~idx, dist, x, y} + z for its own point to the wave's LDS slot.
__device__ __forceinline__ void reduce_phase(float mv, const f32x2 (&X)[8], const f32x2 (&Y)[8],
                                             const f32x2 (&Z)[8], const f32x2 (&M)[8],
                                             int tid, int lane, int wv,
                                             f32x4* svec_slot, float* svz_slot) {
  float wmax = wave_fmax(mv);
  u64 bal = __ballot(mv == wmax);
  int L = (int)__builtin_ctzll(bal);
  u32 em = 0;
#pragma unroll
  for (int j = 0; j < 8; ++j) {
    if (M[j].x == mv) em |= 1u << (2 * j);
    if (M[j].y == mv) em |= 1u << (2 * j + 1);
  }
  u32 eo = (u32)__builtin_ctz(em);          // own first-match element, 0..15 (em != 0 always)
  u32 jj = eo >> 1;
  f32x2 xs = jj == 0 ? X[0] : jj == 1 ? X[1] : jj == 2 ? X[2] : jj == 3 ? X[3]
           : jj == 4 ? X[4] : jj == 5 ? X[5] : jj == 6 ? X[6] : X[7];
  f32x2 ys = jj == 0 ? Y[0] : jj == 1 ? Y[1] : jj == 2 ? Y[2] : jj == 3 ? Y[3]
           : jj == 4 ? Y[4] : jj == 5 ? Y[5] : jj == 6 ? Y[6] : Y[7];
  f32x2 zs = jj == 0 ? Z[0] : jj == 1 ? Z[1] : jj == 2 ? Z[2] : jj == 3 ? Z[3]
           : jj == 4 ? Z[4] : jj == 5 ? Z[5] : jj == 6 ? Z[6] : Z[7];
  float lx = (eo & 1) ? xs.y : xs.x;
  float ly = (eo & 1) ? ys.y : ys.x;
  float lz = (eo & 1) ? zs.y : zs.x;
  if (lane == L) {
    f32x4 ev;
    ev[0] = __uint_as_float(~(u32)(tid * 16 + eo));
    ev[1] = wmax;
    ev[2] = lx;
    ev[3] = ly;
    svec_slot[wv] = ev;
    svz_slot[wv] = lz;
  }
}

// cross-wave resolve (f64 max over 4 keys), write center to LDS buffer, update minds.
__device__ __forceinline__ float resolve_update(f32x2 (&X)[8], f32x2 (&Y)[8], f32x2 (&Z)[8],
                                                f32x2 (&M)[8], const f32x4* svec_slot,
                                                const float* svz_slot, int tid, int m,
                                                float* scen_b) {
  f32x4 e0 = svec_slot[0], e1 = svec_slot[1], e2 = svec_slot[2], e3 = svec_slot[3];
  f32x4 zv = *(const f32x4*)svz_slot;
  double kb = fmax(fmax(keyd(e0), keyd(e1)), fmax(keyd(e2), keyd(e3)));
  u64 kbu = __builtin_bit_cast(u64, kb);
  u32 bp = ~(u32)kbu;                 // winning point index
  u32 w = bp >> 10;                   // winning wave (wave owns 1024 contiguous points)
  float s0 = (w & 1) ? e1[2] : e0[2], s1 = (w & 1) ? e3[2] : e2[2];
  float ncx = (w & 2) ? s1 : s0;
  float t0 = (w & 1) ? e1[3] : e0[3], t1 = (w & 1) ? e3[3] : e2[3];
  float ncy = (w & 2) ? t1 : t0;
  float u0 = (w & 1) ? zv[1] : zv[0], u1 = (w & 1) ? zv[3] : zv[2];
  float ncz = (w & 2) ? u1 : u0;
  if (tid == 0) {
    scen_b[m * 3 + 0] = ncx;
    scen_b[m * 3 + 1] = ncy;
    scen_b[m * 3 + 2] = ncz;
  }
  f32x2 rm;
  {
#pragma clang fp contract(off)
    f32x2 vcx; vcx.x = ncx; vcx.y = ncx;
    f32x2 vcy; vcy.x = ncy; vcy.y = ncy;
    f32x2 vcz; vcz.x = ncz; vcz.y = ncz;
#pragma unroll
    for (int j = 0; j < 8; ++j) {
      f32x2 dx = X[j] - vcx, dy = Y[j] - vcy, dz = Z[j] - vcz;
      f32x2 d2 = (dx * dx + dy * dy) + dz * dz;
      M[j] = __builtin_elementwise_min(M[j], d2);
      rm = j ? __builtin_elementwise_max(rm, M[j]) : M[j];
    }
  }
  return fmaxf(rm.x, rm.y);
}

__device__ __forceinline__ float init_m(const f32x2 (&X)[8], const f32x2 (&Y)[8],
                                        const f32x2 (&Z)[8], f32x2 (&M)[8],
                                        float cx, float cy, float cz) {
  f32x2 rm;
  {
#pragma clang fp contract(off)
    f32x2 vcx; vcx.x = cx; vcx.y = cx;
    f32x2 vcy; vcy.x = cy; vcy.y = cy;
    f32x2 vcz; vcz.x = cz; vcz.y = cz;
#pragma unroll
    for (int j = 0; j < 8; ++j) {
      f32x2 dx = X[j] - vcx, dy = Y[j] - vcy, dz = Z[j] - vcz;
      M[j] = (dx * dx + dy * dy) + dz * dz;
      rm = j ? __builtin_elementwise_max(rm, M[j]) : M[j];
    }
  }
  return fmaxf(rm.x, rm.y);
}

// ---------------- FPS: 4 blocks x 256 threads; each block interleaves TWO batches ----------------
__global__ __launch_bounds__(256) void fps2_k(const float* __restrict__ pos,
                                              float* __restrict__ centers) {
  const int bA = blockIdx.x * 2, bB = bA + 1;
  const int tid = threadIdx.x;
  const int lane = tid & 63;
  const int wv = tid >> 6;               // 0..3
  __shared__ __align__(16) f32x4 svec[2][2][4];   // [pingpong][batch][wave] {~idx,dist,x,y}
  __shared__ __align__(16) float svz[2][2][4];    // z per wave
  __shared__ float scen[2][MM * 3];               // buffered centers

  const float* PA = pos + (size_t)bA * NN * 3;
  const float* PB = pos + (size_t)bB * NN * 3;

  // thread t owns points [t*16, t*16+16) of each batch (lexicographic order preserved)
  f32x2 XA[8], YA[8], ZA[8], MA[8], XB[8], YB[8], ZB[8], MB[8];
#pragma unroll
  for (int j = 0; j < 8; ++j) {
    int p0 = tid * 16 + j * 2;
    XA[j].x = PA[p0 * 3 + 0]; YA[j].x = PA[p0 * 3 + 1]; ZA[j].x = PA[p0 * 3 + 2];
    XA[j].y = PA[p0 * 3 + 3]; YA[j].y = PA[p0 * 3 + 4]; ZA[j].y = PA[p0 * 3 + 5];
    XB[j].x = PB[p0 * 3 + 0]; YB[j].x = PB[p0 * 3 + 1]; ZB[j].x = PB[p0 * 3 + 2];
    XB[j].y = PB[p0 * 3 + 3]; YB[j].y = PB[p0 * 3 + 4]; ZB[j].y = PB[p0 * 3 + 5];
  }
#pragma unroll
  for (int j = 0; j < 8; ++j) {
    asm volatile("" : "+v"(XA[j]), "+v"(YA[j]), "+v"(ZA[j]));
    asm volatile("" : "+v"(XB[j]), "+v"(YB[j]), "+v"(ZB[j]));
  }

  const float cAx = PA[0], cAy = PA[1], cAz = PA[2];
  const float cBx = PB[0], cBy = PB[1], cBz = PB[2];
  float mvA = init_m(XA, YA, ZA, MA, cAx, cAy, cAz);
  float mvB = init_m(XB, YB, ZB, MB, cBx, cBy, cBz);
  if (tid == 0) {
    scen[0][0] = cAx; scen[0][1] = cAy; scen[0][2] = cAz;
    scen[1][0] = cBx; scen[1][1] = cBy; scen[1][2] = cBz;
  }

  for (int m = 1; m < MM; ++m) {
    const int pp = m & 1;
    reduce_phase(mvA, XA, YA, ZA, MA, tid, lane, wv, &svec[pp][0][0], &svz[pp][0][0]);
    reduce_phase(mvB, XB, YB, ZB, MB, tid, lane, wv, &svec[pp][1][0], &svz[pp][1][0]);
    __syncthreads();
    mvA = resolve_update(XA, YA, ZA, MA, &svec[pp][0][0], &svz[pp][0][0], tid, m, scen[0]);
    mvB = resolve_update(XB, YB, ZB, MB, &svec[pp][1][0], &svz[pp][1][0], tid, m, scen[1]);
  }
  __syncthreads();
  for (int i = tid; i < MM * 3; i += 256) {
    centers[(size_t)bA * MM * 3 + i] = scen[0][i];
    centers[(size_t)bB * MM * 3 + i] = scen[1][i];
  }
}

// ---------------- fused ball query + PointNetConv MLP: one block per center ----------------
__global__ __launch_bounds__(256) void sa_k(const float* __restrict__ x,
                                            const float* __restrict__ pos,
                                            const float* __restrict__ b1,
                                            const float* __restrict__ b2,
                                            const short* __restrict__ W1T,
                                            const short* __restrict__ W2T,
                                            const float* __restrict__ centers,
                                            float* __restrict__ out) {
  const int cm = blockIdx.x;      // b*MM + m
  const int b = cm >> 10;         // / MM
  const int tid = threadIdx.x;
  const int lane = tid & 63, wv = tid >> 6;
  const int l15 = lane & 15, lg = lane >> 4;

  __shared__ short s_feat[64][104];
  __shared__ short s_h1[64][136];
  __shared__ int s_nbr[64];
  __shared__ int s_wcnt[4];

  // --- weight fragments in registers (B-operand): row=n (lane&15), k contiguous 8 ---
  const int n0 = wv * 32;
  short8 w1f[2][3], w2f[2][4];
#pragma unroll
  for (int nt = 0; nt < 2; ++nt) {
    int row = n0 + nt * 16 + l15;
#pragma unroll
    for (int kt = 0; kt < 3; ++kt)
      w1f[nt][kt] = *reinterpret_cast<const short8*>(W1T + row * 104 + kt * 32 + lg * 8);
#pragma unroll
    for (int kt = 0; kt < 4; ++kt)
      w2f[nt][kt] = *reinterpret_cast<const short8*>(W2T + row * 136 + kt * 32 + lg * 8);
  }

  const float* Pb = pos + (size_t)b * NN * 3;
  const float cx = centers[(size_t)cm * 3 + 0];
  const float cy = centers[(size_t)cm * 3 + 1];
  const float cz = centers[(size_t)cm * 3 + 2];

  // --- ball query: first KK in index order with d2 <= 0.04f ---
  int cnt = 0;
  for (int base = 0; base < NN; base += 256) {
    int p = base + tid;
    float d2 = sqd(Pb[p * 3 + 0], Pb[p * 3 + 1], Pb[p * 3 + 2], cx, cy, cz);
    bool pred = d2 <= 0.04f;   // float32(0.04), matches reference R*R cast
    unsigned long long mask = __ballot(pred);
    if (lane == 0) s_wcnt[wv] = __popcll(mask);
    __syncthreads();
    int wbase = cnt, tot = 0;
#pragma unroll
    for (int w = 0; w < 4; ++w) {
      int c = s_wcnt[w];
      tot += c;
      if (w < wv) wbase += c;
    }
    if (pred) {
      int slot = wbase + (int)__popcll(mask & ((1ull << lane) - 1ull));
      if (slot < KK) s_nbr[slot] = p;
    }
    cnt += tot;
    __syncthreads();
    if (cnt >= KK) break;
  }
  if (cnt > KK) cnt = KK;

  // --- zero feat (covers padding cols + invalid rows), then gather ---
  {
    int* fz = (int*)&s_feat[0][0];
    for (int i = tid; i < 64 * 104 / 2; i += 256) fz[i] = 0;
  }
  __syncthreads();

  {
    const int j = tid >> 2, q = tid & 3;   // 64 neighbors x 4 thread-chunks of 16 feats
    if (j < cnt) {
      int nj = s_nbr[j];
      const float* xr = x + ((size_t)b * NN + nj) * CC + q * 16;
      unsigned* dst = (unsigned*)&s_feat[j][q * 16];
#pragma unroll
      for (int v4 = 0; v4 < 4; ++v4) {
        f32x4 xv = *reinterpret_cast<const f32x4*>(xr + v4 * 4);
        unsigned lo0 = (unsigned)f2bf(xv[0]) | ((unsigned)f2bf(xv[1]) << 16);
        unsigned lo1 = (unsigned)f2bf(xv[2]) | ((unsigned)f2bf(xv[3]) << 16);
        dst[v4 * 2 + 0] = lo0;
        dst[v4 * 2 + 1] = lo1;
      }
      if (q == 0) {
        s_feat[j][64] = (short)f2bf(__fsub_rn(Pb[nj * 3 + 0], cx));
        s_feat[j][65] = (short)f2bf(__fsub_rn(Pb[nj * 3 + 1], cy));
        s_feat[j][66] = (short)f2bf(__fsub_rn(Pb[nj * 3 + 2], cz));
      }
    }
  }
  __syncthreads();

  // --- layer 1: feat[64x96] @ W1T -> h1[64][128] (per-wave 32 cols) ---
  f32x4 acc[4][2];
#pragma unroll
  for (int mt = 0; mt < 4; ++mt)
#pragma unroll
    for (int nt = 0; nt < 2; ++nt) acc[mt][nt] = (f32x4)0.f;

#pragma unroll
  for (int mt = 0; mt < 4; ++mt) {
    int arow = mt * 16 + l15;
#pragma unroll
    for (int kt = 0; kt < 3; ++kt) {
      short8 af = *reinterpret_cast<const short8*>(&s_feat[arow][kt * 32 + lg * 8]);
      acc[mt][0] = __builtin_amdgcn_mfma_f32_16x16x32_bf16(af, w1f[0][kt], acc[mt][0], 0, 0, 0);
      acc[mt][1] = __builtin_amdgcn_mfma_f32_16x16x32_bf16(af, w1f[1][kt], acc[mt][1], 0, 0, 0);
    }
  }

  // bias + relu -> bf16 h1 in LDS
#pragma unroll
  for (int mt = 0; mt < 4; ++mt) {
#pragma unroll
    for (int nt = 0; nt < 2; ++nt) {
      int col = n0 + nt * 16 + l15;
      float bias = b1[col];
#pragma unroll
      for (int r = 0; r < 4; ++r) {
        int row = mt * 16 + lg * 4 + r;
        float h = fmaxf(__fadd_rn(acc[mt][nt][r], bias), 0.f);
        s_h1[row][col] = (short)f2bf(h);
      }
    }
  }
  __syncthreads();

  // --- layer 2: h1[64x128] @ W2T ---
  f32x4 acc2[4][2];
#pragma unroll
  for (int mt = 0; mt < 4; ++mt)
#pragma unroll
    for (int nt = 0; nt < 2; ++nt) acc2[mt][nt] = (f32x4)0.f;

#pragma unroll
  for (int mt = 0; mt < 4; ++mt) {
    int arow = mt * 16 + l15;
#pragma unroll
    for (int kt = 0; kt < 4; ++kt) {
      short8 af = *reinterpret_cast<const short8*>(&s_h1[arow][kt * 32 + lg * 8]);
      acc2[mt][0] = __builtin_amdgcn_mfma_f32_16x16x32_bf16(af, w2f[0][kt], acc2[mt][0], 0, 0, 0);
      acc2[mt][1] = __builtin_amdgcn_mfma_f32_16x16x32_bf16(af, w2f[1][kt], acc2[mt][1], 0, 0, 0);
    }
  }

  // --- bias + relu + masked max over neighbors, then write out[cm][col] ---
#pragma unroll
  for (int nt = 0; nt < 2; ++nt) {
    int col = n0 + nt * 16 + l15;
    float bias = b2[col];
    float mx = -1e30f;
#pragma unroll
    for (int mt = 0; mt < 4; ++mt) {
#pragma unroll
      for (int r = 0; r < 4; ++r) {
        int row = mt * 16 + lg * 4 + r;
        float h = fmaxf(__fadd_rn(acc2[mt][nt][r], bias), 0.f);
        if (row < cnt) mx = fmaxf(mx, h);
      }
    }
    mx = fmaxf(mx, __shfl_xor(mx, 16));
    mx = fmaxf(mx, __shfl_xor(mx, 32));
    if (lg == 0) out[(size_t)cm * HH + col] = mx;
  }
}

extern "C" void kernel_launch(void* const* d_in, const int* in_sizes, int n_in,
                              void* d_out, int out_size, void* d_ws, size_t ws_size,
                              hipStream_t stream) {
  const float* x = (const float*)d_in[0];
  const float* pos = (const float*)d_in[1];
  const float* W1 = (const float*)d_in[2];
  const float* b1 = (const float*)d_in[3];
  const float* W2 = (const float*)d_in[4];
  const float* b2 = (const float*)d_in[5];

  float* out = (float*)d_out;
  float* centers = out + (size_t)BN * MM * HH;

  char* ws = (char*)d_ws;
  short* W1T = (short*)ws;                    // 128*104*2 = 26624 B
  short* W2T = (short*)(ws + 26624);          // 128*136*2 = 34816 B

  prep_w<<<68, 256, 0, stream>>>(W1, W2, W1T, W2T);
  fps2_k<<<BN / 2, 256, 0, stream>>>(pos, centers);
  sa_k<<<BN * MM, 256, 0, stream>>>(x, pos, b1, b2, W1T, W2T, centers, out);
}

// Round 7
// 1137.960 us; speedup vs baseline: 2.6462x; 2.6462x over previous
//
#include <hip/hip_runtime.h>

#define BN 8
#define NN 4096
#define CC 64
#define MM 1024
#define KK 64
#define HH 128

typedef __attribute__((ext_vector_type(8))) short short8;
typedef __attribute__((ext_vector_type(4))) float f32x4;
typedef __attribute__((ext_vector_type(2))) float f32x2;
typedef unsigned long long u64;
typedef unsigned int u32;

__device__ inline unsigned short f2bf(float f) {
  union { float f; unsigned u; } v; v.f = f;
  unsigned r = v.u + 0x7FFFu + ((v.u >> 16) & 1u);
  return (unsigned short)(r >> 16);
}

// squared distance with NO fma contraction, numpy op order: (dx*dx + dy*dy) + dz*dz
__device__ inline float sqd(float ax, float ay, float az, float bx, float by, float bz) {
  float dx = __fsub_rn(ax, bx), dy = __fsub_rn(ay, by), dz = __fsub_rn(az, bz);
  return __fadd_rn(__fadd_rn(__fmul_rn(dx, dx), __fmul_rn(dy, dy)), __fmul_rn(dz, dz));
}

// ---------------- weight prep: transpose + pad + bf16 ----------------
__global__ void prep_w(const float* __restrict__ W1, const float* __restrict__ W2,
                       short* __restrict__ W1T, short* __restrict__ W2T) {
  int t = blockIdx.x * 256 + threadIdx.x;
  if (t < 128 * 104) {
    int n = t / 104, k = t % 104;
    float v = (k < 67) ? W1[k * 128 + n] : 0.f;
    W1T[t] = (short)f2bf(v);
  }
  if (t < 128 * 136) {
    int n = t / 136, k = t % 136;
    float v = (k < 128) ? W2[k * 128 + n] : 0.f;
    W2T[t] = (short)f2bf(v);
  }
}

// ---- DPP-based wave max of f32 (result broadcast via readlane 63) ----
template <int CTRL, int RM>
__device__ __forceinline__ float dppf(float x) {
  int v = __builtin_amdgcn_update_dpp(0, __float_as_int(x), CTRL, RM, 0xF, false);
  return __int_as_float(v);
}

__device__ __forceinline__ float wave_fmax(float x) {
  x = fmaxf(x, dppf<0xB1, 0xF>(x));    // quad_perm xor1
  x = fmaxf(x, dppf<0x4E, 0xF>(x));    // quad_perm xor2
  x = fmaxf(x, dppf<0x141, 0xF>(x));   // row_half_mirror
  x = fmaxf(x, dppf<0x140, 0xF>(x));   // row_mirror
  x = fmaxf(x, dppf<0x142, 0xA>(x));   // row_bcast15 -> rows 1,3
  x = fmaxf(x, dppf<0x143, 0xC>(x));   // row_bcast31 -> rows 2,3
  return __int_as_float(__builtin_amdgcn_readlane(__float_as_int(x), 63));
}

__device__ __forceinline__ double keyd(f32x4 e) {
  f32x2 p; p.x = e[0]; p.y = e[1];
  return __builtin_bit_cast(double, p);
}

// ---------------- FPS: one block per batch, 512 threads, 8 contiguous pts/thread ----------------
// f32 wave max + carried winner coords + f64-key cross-wave resolve; 1 barrier/step.
__global__ __launch_bounds__(512) void fps_k(const float* __restrict__ pos,
                                             float* __restrict__ centers) {
  const int b = blockIdx.x;
  const int tid = threadIdx.x;
  const int lane = tid & 63;
  const int wv = tid >> 6;                    // 0..7
  __shared__ __align__(16) double svk[2][8];  // per-wave key {hi=dist bits, lo=~idx}
  __shared__ __align__(16) f32x4 svc[2][8];   // per-wave winner coords {x,y,z,-}
  __shared__ float scen[MM * 3];              // buffered centers

  const float* P = pos + (size_t)b * NN * 3;

  // thread t owns points [t*8, t*8+8): point order == (thread, elem) lexicographic
  f32x2 X[4], Y[4], Z[4], M[4];
#pragma unroll
  for (int j = 0; j < 4; ++j) {
    int p0 = tid * 8 + j * 2;
    X[j].x = P[p0 * 3 + 0]; Y[j].x = P[p0 * 3 + 1]; Z[j].x = P[p0 * 3 + 2];
    X[j].y = P[p0 * 3 + 3]; Y[j].y = P[p0 * 3 + 4]; Z[j].y = P[p0 * 3 + 5];
  }
#pragma unroll
  for (int j = 0; j < 4; ++j)
    asm volatile("" : "+v"(X[j]), "+v"(Y[j]), "+v"(Z[j]));

  const float c0x = P[0], c0y = P[1], c0z = P[2];
  float mv;
  {
#pragma clang fp contract(off)
    f32x2 vcx; vcx.x = c0x; vcx.y = c0x;
    f32x2 vcy; vcy.x = c0y; vcy.y = c0y;
    f32x2 vcz; vcz.x = c0z; vcz.y = c0z;
    f32x2 rm;
#pragma unroll
    for (int j = 0; j < 4; ++j) {
      f32x2 dx = X[j] - vcx, dy = Y[j] - vcy, dz = Z[j] - vcz;
      M[j] = (dx * dx + dy * dy) + dz * dz;
      rm = j ? __builtin_elementwise_max(rm, M[j]) : M[j];
    }
    mv = fmaxf(rm.x, rm.y);
  }
  if (tid == 0) { scen[0] = c0x; scen[1] = c0y; scen[2] = c0z; }
  __syncthreads();

  for (int m = 1; m < MM; ++m) {
    const int pp = m & 1;
    // wave max of per-thread max
    float wmax = wave_fmax(mv);
    u64 bal = __ballot(mv == wmax);
    int L = (int)__builtin_ctzll(bal);        // lowest lane -> lowest point range
    // own first-match element (em != 0 always: mv is this thread's own max)
    u32 em = 0;
#pragma unroll
    for (int j = 0; j < 4; ++j) {
      if (M[j].x == mv) em |= 1u << (2 * j);
      if (M[j].y == mv) em |= 1u << (2 * j + 1);
    }
    u32 eo = (u32)__builtin_ctz(em);
    u32 jj = eo >> 1;
    f32x2 xs = (jj & 2) ? ((jj & 1) ? X[3] : X[2]) : ((jj & 1) ? X[1] : X[0]);
    f32x2 ys = (jj & 2) ? ((jj & 1) ? Y[3] : Y[2]) : ((jj & 1) ? Y[1] : Y[0]);
    f32x2 zs = (jj & 2) ? ((jj & 1) ? Z[3] : Z[2]) : ((jj & 1) ? Z[1] : Z[0]);
    float lx = (eo & 1) ? xs.y : xs.x;
    float ly = (eo & 1) ? ys.y : ys.x;
    float lz = (eo & 1) ? zs.y : zs.x;
    if (lane == L) {
      u64 kk = ((u64)__float_as_uint(wmax) << 32) | (u64)(u32)~(u32)(tid * 8 + eo);
      svk[pp][wv] = __builtin_bit_cast(double, kk);
      f32x4 cv; cv[0] = lx; cv[1] = ly; cv[2] = lz; cv[3] = 0.f;
      svc[pp][wv] = cv;
    }
    __syncthreads();
    // parallel reads of all keys + coords (broadcast)
    const f32x4* kp = (const f32x4*)&svk[pp][0];
    f32x4 k01 = kp[0], k23 = kp[1], k45 = kp[2], k67 = kp[3];
    f32x4 q0 = svc[pp][0], q1 = svc[pp][1], q2 = svc[pp][2], q3 = svc[pp][3];
    f32x4 q4 = svc[pp][4], q5 = svc[pp][5], q6 = svc[pp][6], q7 = svc[pp][7];
    f32x2 klo, khi;
    klo.x = k01[0]; klo.y = k01[1]; khi.x = k01[2]; khi.y = k01[3];
    double d0 = __builtin_bit_cast(double, klo), d1 = __builtin_bit_cast(double, khi);
    klo.x = k23[0]; klo.y = k23[1]; khi.x = k23[2]; khi.y = k23[3];
    double d2 = __builtin_bit_cast(double, klo), d3 = __builtin_bit_cast(double, khi);
    klo.x = k45[0]; klo.y = k45[1]; khi.x = k45[2]; khi.y = k45[3];
    double d4 = __builtin_bit_cast(double, klo), d5 = __builtin_bit_cast(double, khi);
    klo.x = k67[0]; klo.y = k67[1]; khi.x = k67[2]; khi.y = k67[3];
    double d6 = __builtin_bit_cast(double, klo), d7 = __builtin_bit_cast(double, khi);
    double kb = fmax(fmax(fmax(d0, d1), fmax(d2, d3)), fmax(fmax(d4, d5), fmax(d6, d7)));
    u64 kbu = __builtin_bit_cast(u64, kb);
    u32 w = (~(u32)kbu) >> 9;                 // winning wave (512 pts per wave)
    // 3-level select of winner coords
    f32x4 s0 = (w & 1) ? q1 : q0, s1 = (w & 1) ? q3 : q2;
    f32x4 s2 = (w & 1) ? q5 : q4, s3 = (w & 1) ? q7 : q6;
    f32x4 t0 = (w & 2) ? s1 : s0, t1 = (w & 2) ? s3 : s2;
    f32x4 cw = (w & 4) ? t1 : t0;
    const float ncx = cw[0], ncy = cw[1], ncz = cw[2];
    if (tid == 0) {
      scen[m * 3 + 0] = ncx;
      scen[m * 3 + 1] = ncy;
      scen[m * 3 + 2] = ncz;
    }
    // update minds + fold next thread-local max
    {
#pragma clang fp contract(off)
      f32x2 vcx; vcx.x = ncx; vcx.y = ncx;
      f32x2 vcy; vcy.x = ncy; vcy.y = ncy;
      f32x2 vcz; vcz.x = ncz; vcz.y = ncz;
      f32x2 rm;
#pragma unroll
      for (int j = 0; j < 4; ++j) {
        f32x2 dx = X[j] - vcx, dy = Y[j] - vcy, dz = Z[j] - vcz;
        f32x2 d2 = (dx * dx + dy * dy) + dz * dz;
        M[j] = __builtin_elementwise_min(M[j], d2);
        rm = j ? __builtin_elementwise_max(rm, M[j]) : M[j];
      }
      mv = fmaxf(rm.x, rm.y);
    }
  }
  __syncthreads();
  for (int i = tid; i < MM * 3; i += 512)
    centers[(size_t)b * MM * 3 + i] = scen[i];
}

// ---------------- fused ball query + PointNetConv MLP: one block per center ----------------
__global__ __launch_bounds__(256) void sa_k(const float* __restrict__ x,
                                            const float* __restrict__ pos,
                                            const float* __restrict__ b1,
                                            const float* __restrict__ b2,
                                            const short* __restrict__ W1T,
                                            const short* __restrict__ W2T,
                                            const float* __restrict__ centers,
                                            float* __restrict__ out) {
  const int cm = blockIdx.x;      // b*MM + m
  const int b = cm >> 10;         // / MM
  const int tid = threadIdx.x;
  const int lane = tid & 63, wv = tid >> 6;
  const int l15 = lane & 15, lg = lane >> 4;

  __shared__ short s_feat[64][104];
  __shared__ short s_h1[64][136];
  __shared__ int s_nbr[64];
  __shared__ int s_wcnt[4];

  // --- weight fragments in registers (B-operand): row=n (lane&15), k contiguous 8 ---
  const int n0 = wv * 32;
  short8 w1f[2][3], w2f[2][4];
#pragma unroll
  for (int nt = 0; nt < 2; ++nt) {
    int row = n0 + nt * 16 + l15;
#pragma unroll
    for (int kt = 0; kt < 3; ++kt)
      w1f[nt][kt] = *reinterpret_cast<const short8*>(W1T + row * 104 + kt * 32 + lg * 8);
#pragma unroll
    for (int kt = 0; kt < 4; ++kt)
      w2f[nt][kt] = *reinterpret_cast<const short8*>(W2T + row * 136 + kt * 32 + lg * 8);
  }

  const float* Pb = pos + (size_t)b * NN * 3;
  const float cx = centers[(size_t)cm * 3 + 0];
  const float cy = centers[(size_t)cm * 3 + 1];
  const float cz = centers[(size_t)cm * 3 + 2];

  // --- ball query: first KK in index order with d2 <= 0.04f ---
  int cnt = 0;
  for (int base = 0; base < NN; base += 256) {
    int p = base + tid;
    float d2 = sqd(Pb[p * 3 + 0], Pb[p * 3 + 1], Pb[p * 3 + 2], cx, cy, cz);
    bool pred = d2 <= 0.04f;   // float32(0.04), matches reference R*R cast
    unsigned long long mask = __ballot(pred);
    if (lane == 0) s_wcnt[wv] = __popcll(mask);
    __syncthreads();
    int wbase = cnt, tot = 0;
#pragma unroll
    for (int w = 0; w < 4; ++w) {
      int c = s_wcnt[w];
      tot += c;
      if (w < wv) wbase += c;
    }
    if (pred) {
      int slot = wbase + (int)__popcll(mask & ((1ull << lane) - 1ull));
      if (slot < KK) s_nbr[slot] = p;
    }
    cnt += tot;
    __syncthreads();
    if (cnt >= KK) break;
  }
  if (cnt > KK) cnt = KK;

  // --- zero feat (covers padding cols + invalid rows), then gather ---
  {
    int* fz = (int*)&s_feat[0][0];
    for (int i = tid; i < 64 * 104 / 2; i += 256) fz[i] = 0;
  }
  __syncthreads();

  {
    const int j = tid >> 2, q = tid & 3;   // 64 neighbors x 4 thread-chunks of 16 feats
    if (j < cnt) {
      int nj = s_nbr[j];
      const float* xr = x + ((size_t)b * NN + nj) * CC + q * 16;
      unsigned* dst = (unsigned*)&s_feat[j][q * 16];
#pragma unroll
      for (int v4 = 0; v4 < 4; ++v4) {
        f32x4 xv = *reinterpret_cast<const f32x4*>(xr + v4 * 4);
        unsigned lo0 = (unsigned)f2bf(xv[0]) | ((unsigned)f2bf(xv[1]) << 16);
        unsigned lo1 = (unsigned)f2bf(xv[2]) | ((unsigned)f2bf(xv[3]) << 16);
        dst[v4 * 2 + 0] = lo0;
        dst[v4 * 2 + 1] = lo1;
      }
      if (q == 0) {
        s_feat[j][64] = (short)f2bf(__fsub_rn(Pb[nj * 3 + 0], cx));
        s_feat[j][65] = (short)f2bf(__fsub_rn(Pb[nj * 3 + 1], cy));
        s_feat[j][66] = (short)f2bf(__fsub_rn(Pb[nj * 3 + 2], cz));
      }
    }
  }
  __syncthreads();

  // --- layer 1: feat[64x96] @ W1T -> h1[64][128] (per-wave 32 cols) ---
  f32x4 acc[4][2];
#pragma unroll
  for (int mt = 0; mt < 4; ++mt)
#pragma unroll
    for (int nt = 0; nt < 2; ++nt) acc[mt][nt] = (f32x4)0.f;

#pragma unroll
  for (int mt = 0; mt < 4; ++mt) {
    int arow = mt * 16 + l15;
#pragma unroll
    for (int kt = 0; kt < 3; ++kt) {
      short8 af = *reinterpret_cast<const short8*>(&s_feat[arow][kt * 32 + lg * 8]);
      acc[mt][0] = __builtin_amdgcn_mfma_f32_16x16x32_bf16(af, w1f[0][kt], acc[mt][0], 0, 0, 0);
      acc[mt][1] = __builtin_amdgcn_mfma_f32_16x16x32_bf16(af, w1f[1][kt], acc[mt][1], 0, 0, 0);
    }
  }

  // bias + relu -> bf16 h1 in LDS
#pragma unroll
  for (int mt = 0; mt < 4; ++mt) {
#pragma unroll
    for (int nt = 0; nt < 2; ++nt) {
      int col = n0 + nt * 16 + l15;
      float bias = b1[col];
#pragma unroll
      for (int r = 0; r < 4; ++r) {
        int row = mt * 16 + lg * 4 + r;
        float h = fmaxf(__fadd_rn(acc[mt][nt][r], bias), 0.f);
        s_h1[row][col] = (short)f2bf(h);
      }
    }
  }
  __syncthreads();

  // --- layer 2: h1[64x128] @ W2T ---
  f32x4 acc2[4][2];
#pragma unroll
  for (int mt = 0; mt < 4; ++mt)
#pragma unroll
    for (int nt = 0; nt < 2; ++nt) acc2[mt][nt] = (f32x4)0.f;

#pragma unroll
  for (int mt = 0; mt < 4; ++mt) {
    int arow = mt * 16 + l15;
#pragma unroll
    for (int kt = 0; kt < 4; ++kt) {
      short8 af = *reinterpret_cast<const short8*>(&s_h1[arow][kt * 32 + lg * 8]);
      acc2[mt][0] = __builtin_amdgcn_mfma_f32_16x16x32_bf16(af, w2f[0][kt], acc2[mt][0], 0, 0, 0);
      acc2[mt][1] = __builtin_amdgcn_mfma_f32_16x16x32_bf16(af, w2f[1][kt], acc2[mt][1], 0, 0, 0);
    }
  }

  // --- bias + relu + masked max over neighbors, then write out[cm][col] ---
#pragma unroll
  for (int nt = 0; nt < 2; ++nt) {
    int col = n0 + nt * 16 + l15;
    float bias = b2[col];
    float mx = -1e30f;
#pragma unroll
    for (int mt = 0; mt < 4; ++mt) {
#pragma unroll
      for (int r = 0; r < 4; ++r) {
        int row = mt * 16 + lg * 4 + r;
        float h = fmaxf(__fadd_rn(acc2[mt][nt][r], bias), 0.f);
        if (row < cnt) mx = fmaxf(mx, h);
      }
    }
    mx = fmaxf(mx, __shfl_xor(mx, 16));
    mx = fmaxf(mx, __shfl_xor(mx, 32));
    if (lg == 0) out[(size_t)cm * HH + col] = mx;
  }
}

extern "C" void kernel_launch(void* const* d_in, const int* in_sizes, int n_in,
                              void* d_out, int out_size, void* d_ws, size_t ws_size,
                              hipStream_t stream) {
  const float* x = (const float*)d_in[0];
  const float* pos = (const float*)d_in[1];
  const float* W1 = (const float*)d_in[2];
  const float* b1 = (const float*)d_in[3];
  const float* W2 = (const float*)d_in[4];
  const float* b2 = (const float*)d_in[5];

  float* out = (float*)d_out;
  float* centers = out + (size_t)BN * MM * HH;

  char* ws = (char*)d_ws;
  short* W1T = (short*)ws;                    // 128*104*2 = 26624 B
  short* W2T = (short*)(ws + 26624);          // 128*136*2 = 34816 B

  prep_w<<<68, 256, 0, stream>>>(W1, W2, W1T, W2T);
  fps_k<<<BN, 512, 0, stream>>>(pos, centers);
  sa_k<<<BN * MM, 256, 0, stream>>>(x, pos, b1, b2, W1T, W2T, centers, out);
}